// Round 1
// baseline (2297.305 us; speedup 1.0000x reference)
//
#include <hip/hip_runtime.h>
#include <hip/hip_bf16.h>

typedef __bf16 bf16x8 __attribute__((ext_vector_type(8)));
typedef __bf16 bf16x4 __attribute__((ext_vector_type(4)));
typedef float  f32x4  __attribute__((ext_vector_type(4)));
typedef unsigned int u32x4 __attribute__((ext_vector_type(4)));
typedef unsigned int u32x2 __attribute__((ext_vector_type(2)));

#define T_STEPS 1024
#define LOG2E 1.4426950408889634f

// LDS-only barrier: orders ds ops across the workgroup WITHOUT the vmcnt(0)
// drain __syncthreads() emits; global loads/stores stay in flight.
#define LDS_BARRIER() asm volatile("s_waitcnt lgkmcnt(0)\n\ts_barrier" ::: "memory")

__device__ __forceinline__ float fast_sigmoid(float x) {
  float e = __builtin_amdgcn_exp2f(x * -LOG2E);
  return __builtin_amdgcn_rcpf(1.f + e);
}
__device__ __forceinline__ float fast_tanh(float x) {
  float e = __builtin_amdgcn_exp2f(x * (2.f * LOG2E));
  return 1.f - 2.f * __builtin_amdgcn_rcpf(1.f + e);
}
// exact bf16(hi16-of-f32) -> f32 re-embedding, 1 VALU op each
__device__ __forceinline__ float bf_lo(unsigned int u) { return __uint_as_float(u << 16); }
__device__ __forceinline__ float bf_hi(unsigned int u) { return __uint_as_float(u & 0xFFFF0000u); }

// ws layout (all bf16):
//   afrag: [mat(6)][cb(16)][kblk(8)][lane(64)][j(8)]   (393216 elems)
//     mats: 0=W_z 1=W_r 2=W 3=U_z 4=U_r 5=U
//     content = M[k][col], k = kblk*32 + (lane>>4)*8 + j, col = cb*16 + (lane&15)
//   gates: [t*4+g][mat(3)][p(8)][lane(64)][c(2)][i(4)]  (50331648 elems)
//     mat 0=z,1=r,2=h; holds x@W*+b* for batch = g*16 + (lane&15),
//     feature = (2p+c)*16 + (lane>>4)*4 + i  -- i.e. MFMA C-layout.

__global__ __launch_bounds__(256) void prep_frags(
    const float* __restrict__ Wz, const float* __restrict__ Wr, const float* __restrict__ Wh,
    const float* __restrict__ Uz, const float* __restrict__ Ur, const float* __restrict__ Uh,
    __bf16* __restrict__ afrag)
{
  int idx  = blockIdx.x * 256 + threadIdx.x;   // 1536*256 = 393216 exactly
  int mat  = idx >> 16;
  int cb   = (idx >> 12) & 15;
  int kblk = (idx >> 9) & 7;
  int l    = (idx >> 3) & 63;
  int j    = idx & 7;
  int k    = kblk * 32 + (l >> 4) * 8 + j;
  int col  = cb * 16 + (l & 15);
  const float* s = (mat == 0) ? Wz : (mat == 1) ? Wr : (mat == 2) ? Wh
                 : (mat == 3) ? Uz : (mat == 4) ? Ur : Uh;
  afrag[idx] = (__bf16)s[k * 256 + col];
}

// X-projection GEMM: block = one timestep t (1024 blocks, 4 waves).
// Each wave holds x^T B-fragments for all 4 batch groups (128 VGPRs) and
// streams A-fragments from L2 once, reusing each across the 4 groups.
__global__ __launch_bounds__(256) void gemm_x(
    const float* __restrict__ x, const __bf16* __restrict__ afrag,
    const float* __restrict__ bz, const float* __restrict__ br, const float* __restrict__ bh,
    __bf16* __restrict__ gates)
{
  int t = blockIdx.x;                  // timestep
  int tid = threadIdx.x;
  int l = tid & 63, w = tid >> 6;
  int q = l >> 4, m15 = l & 15;

  bf16x8 bfr[4][8];
#pragma unroll
  for (int g = 0; g < 4; g++) {
    const float* xrow = x + ((size_t)t * 64 + g * 16 + m15) * 256 + q * 8;
#pragma unroll
    for (int kb = 0; kb < 8; kb++) {
      f32x4 lo = *(const f32x4*)(xrow + kb * 32);
      f32x4 hi = *(const f32x4*)(xrow + kb * 32 + 4);
      bf16x8 v;
#pragma unroll
      for (int j = 0; j < 4; j++) { v[j] = (__bf16)lo[j]; v[4 + j] = (__bf16)hi[j]; }
      bfr[g][kb] = v;
    }
  }

  const bf16x8* af = (const bf16x8*)afrag;
#pragma unroll 1
  for (int jj = 0; jj < 12; jj++) {
    int nt = w + 4 * jj;
    int mat = nt >> 4, cb = nt & 15;
    f32x4 acc[4];
#pragma unroll
    for (int g = 0; g < 4; g++) acc[g] = (f32x4){0.f, 0.f, 0.f, 0.f};
#pragma unroll
    for (int kb = 0; kb < 8; kb++) {
      bf16x8 a = af[(nt * 8 + kb) * 64 + l];
#pragma unroll
      for (int g = 0; g < 4; g++)
        acc[g] = __builtin_amdgcn_mfma_f32_16x16x32_bf16(a, bfr[g][kb], acc[g], 0, 0, 0);
    }
    const float* bias = (mat == 0) ? bz : (mat == 1) ? br : bh;
    float b4[4];
#pragma unroll
    for (int i = 0; i < 4; i++) b4[i] = bias[cb * 16 + q * 4 + i];
    int p = cb >> 1, c = cb & 1;
#pragma unroll
    for (int g = 0; g < 4; g++) {
      bf16x4 ov;
#pragma unroll
      for (int i = 0; i < 4; i++) ov[i] = (__bf16)(acc[g][i] + b4[i]);
      *(bf16x4*)(gates + ((size_t)t * 4 + g) * 12288 + ((mat * 8 + p) * 64 + l) * 8 + c * 4) = ov;
    }
  }
}

// Recurrent kernel: 4 blocks (batch groups of 16) x 1024 threads (16 waves,
// 4 waves/SIMD for latency hiding). Wave w owns feature colblock w (16
// features). W_z/W_r A-fragments persist in regs (64 VGPRs); U fragments are
// re-streamed from L2 each step, issued under the phase-1 activation VALU so
// their latency hides. h^T/(r*h)^T in LDS B-fragment order. Gate preacts feed
// MFMA as the C initializer. All step pointers advance uniformly (SGPR);
// lane offsets are loop-invariant 32-bit.
__global__ __launch_bounds__(1024) void gru_rec(
    const __bf16* __restrict__ afrag, const __bf16* __restrict__ gates,
    const float* __restrict__ h0, float* __restrict__ out)
{
  __shared__ bf16x8 hfrag[512];    // [kblk(8)][lane(64)]
  __shared__ bf16x8 rhfrag[512];
  int g = blockIdx.x;
  int tid = threadIdx.x;
  int l = tid & 63, w = tid >> 6;       // w = 0..15, colblock = w
  int q = l >> 4, m15 = l & 15;

  // persistent z/r weight A-fragments (64 regs)
  bf16x8 wz[8], wr[8];
  const bf16x8* af = (const bf16x8*)afrag;
#pragma unroll
  for (int kb = 0; kb < 8; kb++) {
    wz[kb] = af[((3 * 16 + w) * 8 + kb) * 64 + l];
    wr[kb] = af[((4 * 16 + w) * 8 + kb) * 64 + l];
  }
  // U fragment stream base (read from L2 every step; afrag is 768 KB, hot)
  const bf16x8* wup = af + ((size_t)(5 * 16 + w) * 8) * 64 + l;

  // h state in fp32 regs: this lane owns batch m15, features 16w+4q+i
  f32x4 hreg = *(const f32x4*)(h0 + 16 * w + 4 * q);

  // packed LDS write slot (bf16x4 units): feature base 16w+4q ->
  // kblk = w>>1, dest lane' = m15 + 16*(2*(w&1) + (q>>1)), half = q&1
  int wrs = (w >> 1) * 128 + (m15 + 16 * (2 * (w & 1) + (q >> 1))) * 2 + (q & 1);
  bf16x4* hf4  = (bf16x4*)hfrag;
  bf16x4* rhf4 = (bf16x4*)rhfrag;

  // init h^T fragment buffer through the write slots (full coverage)
  {
    bf16x4 hv;
#pragma unroll
    for (int i = 0; i < 4; i++) hv[i] = (__bf16)hreg[i];
    hf4[wrs] = hv;
  }
  LDS_BARRIER();

  // uniform step bases (SGPR) + loop-invariant lane offsets (VGPR, 32-bit)
  const int GSTRIDE = 4 * 12288;                    // gates elems per t
  const __bf16* gt_p = gates + (size_t)g * 12288;   // uniform per block
  int go_z = ((0 * 8 + (w >> 1)) * 64 + l) * 8 + (w & 1) * 4;
  int go_r = go_z + 8 * 64 * 8;
  int go_h = go_z + 2 * 8 * 64 * 8;
  const float* out_t = out;                          // uniform, += 64*256/t
  int oo = (g * 16 + m15) * 256 + 16 * w + 4 * q;

  // prefetch t=0 z/r gate preacts (raw bits)
  u32x2 nzu = *(const u32x2*)(gt_p + go_z);
  u32x2 nru = *(const u32x2*)(gt_p + go_r);

#pragma unroll 1
  for (int t = 0; t < T_STEPS; t++) {
    // current-step h-gates (consumed as phase-2 C-init, ~1 phase away)
    u32x2 ghu = *(const u32x2*)(gt_p + go_h);

    // out[t] = hidden entering step t (pre-update), fp32
    *(f32x4*)(out_t + oo) = hreg;
    out_t += 64 * 256;

    // phase 1: z, r preacts; C initialized from gate preacts (exact embed)
    f32x4 az = {bf_lo(nzu.x), bf_hi(nzu.x), bf_lo(nzu.y), bf_hi(nzu.y)};
    f32x4 ar = {bf_lo(nru.x), bf_hi(nru.x), bf_lo(nru.y), bf_hi(nru.y)};
#pragma unroll
    for (int kb = 0; kb < 8; kb++) {
      bf16x8 hb = hfrag[kb * 64 + l];
      az = __builtin_amdgcn_mfma_f32_16x16x32_bf16(wz[kb], hb, az, 0, 0, 0);
      ar = __builtin_amdgcn_mfma_f32_16x16x32_bf16(wr[kb], hb, ar, 0, 0, 0);
    }

    // stream this step's U fragments now: the activation VALU below plus the
    // barrier hide the L2 latency before their phase-2 use.
    bf16x8 wu[8];
#pragma unroll
    for (int kb = 0; kb < 8; kb++) wu[kb] = wup[kb * 64];

    // activations; z kept as bf16 pack across barrier; carry hmr = h - r*h
    f32x4 hmr;
    bf16x4 zb, rhb;
#pragma unroll
    for (int i = 0; i < 4; i++) {
      float z = fast_sigmoid(az[i]);
      float r = fast_sigmoid(ar[i]);
      float rh = r * hreg[i];
      zb[i]  = (__bf16)z;
      rhb[i] = (__bf16)rh;
      hmr[i] = hreg[i] - rh;
    }
    rhf4[wrs] = rhb;

    // z/r regs dead -> prefetch step t+1 (uniform scalar advance; clamped)
    const __bf16* gn_p = gt_p + ((t < T_STEPS - 1) ? GSTRIDE : 0);
    nzu = *(const u32x2*)(gn_p + go_z);
    nru = *(const u32x2*)(gn_p + go_r);
    gt_p = gn_p;
    LDS_BARRIER();

    // phase 2: h_bar preact from (r*h); C initialized from h-gate preacts
    f32x4 ah = {bf_lo(ghu.x), bf_hi(ghu.x), bf_lo(ghu.y), bf_hi(ghu.y)};
#pragma unroll
    for (int kb = 0; kb < 8; kb++) {
      bf16x8 rb = rhfrag[kb * 64 + l];
      ah = __builtin_amdgcn_mfma_f32_16x16x32_bf16(wu[kb], rb, ah, 0, 0, 0);
    }
    bf16x4 nh;
#pragma unroll
    for (int i = 0; i < 4; i++) {
      float hb = fast_tanh(ah[i]);
      float z  = (float)zb[i];
      // h' = (h - r*h) + z*hbar   == (1-r)*h + z*hbar, per reference's (1-r)
      hreg[i] = hmr[i] + z * hb;
      nh[i] = (__bf16)hreg[i];
    }
    hf4[wrs] = nh;
    LDS_BARRIER();
  }
}

extern "C" void kernel_launch(void* const* d_in, const int* in_sizes, int n_in,
                              void* d_out, int out_size, void* d_ws, size_t ws_size,
                              hipStream_t stream)
{
  const float* x  = (const float*)d_in[0];
  const float* Wh = (const float*)d_in[1];
  const float* Uh = (const float*)d_in[2];
  const float* bh = (const float*)d_in[3];
  const float* Wr = (const float*)d_in[4];
  const float* Ur = (const float*)d_in[5];
  const float* br = (const float*)d_in[6];
  const float* Wz = (const float*)d_in[7];
  const float* Uz = (const float*)d_in[8];
  const float* bz = (const float*)d_in[9];
  const float* h0 = (const float*)d_in[10];

  __bf16* afrag = (__bf16*)d_ws;
  __bf16* gates = (__bf16*)d_ws + 393216;
  if (ws_size < (size_t)(393216 + 50331648) * 2) return;  // need ~96.8 MB

  prep_frags<<<1536, 256, 0, stream>>>(Wz, Wr, Wh, Uz, Ur, Uh, afrag);
  gemm_x<<<1024, 256, 0, stream>>>(x, afrag, bz, br, bh, gates);
  gru_rec<<<4, 1024, 0, stream>>>(afrag, gates, h0, (float*)d_out);
}